// Round 9
// baseline (98.771 us; speedup 1.0000x reference)
//
#include <hip/hip_runtime.h>
#include <hip/hip_fp16.h>

// W8X8Linear: per-row int8 quant (x and w), int8 GEMM via MFMA, dequant+bias.
// M=B*S=32768, N=1024, K=1024 (derived from in_sizes at launch).
//
// Exact-replication notes:
//  - jnp.round == round-half-even == rintf (v_rndne_f32)
//  - scale 127.0f/max (fp32 div) then fp32 mul, like the reference
//  - int32 accumulation == reference's fp32 einsum (|acc| < 2^24, exact)
//  - dequant: * (1/16129), fp16 RN cast, fp32 * (xmax*wmax) + bias
//
// R1: dbuf+XCD swizzle: 92us GEMM. R2/R7: counted-vmcnt on coarse 2-barrier
//     structures: NULL both times (T4 needs T3's fine phases — regime gate
//     confirmed). R3: no-LDS reg GEMM: 158us (16-seg loads). R4: coarse
//     "fine-phase" 256^2: 117us (whole-tile staging bursts, write amp).
//     R5: min-waves clamp -> acc spill -> 360us. R6: K-BLOCKED quant layout
//     (contiguous staging) -> 95us total (~63us GEMM).
// R8: real m201-style port: 256^2, 8 waves 4Mx2N (acc[4][8]), BK=64,
//     4 phases/K-tile {2 ds_read || 1-2 stage stmts -> barrier -> setprio
//     8 MFMA -> barrier}, 3 LDS buffers, depth-2 prefetch, vmcnt(4) once
//     per iter (in flight across barriers). Full-line epilogue (512B/row
//     per (m,r)). Grid 512 = 2 rounds/CU -> tail overlap.

typedef int i32x4 __attribute__((ext_vector_type(4)));

#define BM 256
#define BN 256
#define KB 64  // K-bytes per tile = quant layout block size

// -------- quantize: one block per row; OUTPUT IS K-BLOCKED q[kb][row][64] ---
__global__ __launch_bounds__(256) void quant_rows_kernel(
    const float* __restrict__ in, signed char* __restrict__ q,
    float* __restrict__ rowmax, int K, int R) {
  const int row = blockIdx.x;
  const int t = threadIdx.x;
  const size_t base = (size_t)row * K;
  float4 v = reinterpret_cast<const float4*>(in + base)[t];
  float a = fmaxf(fmaxf(fabsf(v.x), fabsf(v.y)), fmaxf(fabsf(v.z), fabsf(v.w)));
#pragma unroll
  for (int off = 32; off > 0; off >>= 1) a = fmaxf(a, __shfl_xor(a, off, 64));
  __shared__ float smax[4];
  if ((t & 63) == 0) smax[t >> 6] = a;
  __syncthreads();
  float m = fmaxf(fmaxf(smax[0], smax[1]), fmaxf(smax[2], smax[3]));
  float s = 127.0f / m;  // fp32 divide, same as reference
  char4 qq;
  qq.x = (signed char)(int)rintf(v.x * s);
  qq.y = (signed char)(int)rintf(v.y * s);
  qq.z = (signed char)(int)rintf(v.z * s);
  qq.w = (signed char)(int)rintf(v.w * s);
  // elems k = 4t..4t+3 -> kb = t>>4, within-block byte (t&15)*4
  const int kb = t >> 4;
  signed char* dst = q + (size_t)kb * R * KB + (size_t)row * KB + (t & 15) * 4;
  *reinterpret_cast<char4*>(dst) = qq;
  if (t == 0) rowmax[row] = m;
}

// ------------- int8 GEMM, 256x256 tile, 8 waves (4M x 2N), BK=64 ------------
__device__ __forceinline__ void gload_lds16(const void* g, void* l) {
  __builtin_amdgcn_global_load_lds(
      (const __attribute__((address_space(1))) unsigned char*)g,
      (__attribute__((address_space(3))) unsigned char*)l, 16, 0, 0);
}

__global__ __launch_bounds__(512) void w8x8_gemm_kernel(
    const signed char* __restrict__ Aq, const signed char* __restrict__ Bq,
    const float* __restrict__ Amax, const float* __restrict__ Bmax,
    const float* __restrict__ bias, float* __restrict__ out,
    int M, int N, int K, int cpx) {
  // 3 K-tile buffers per operand: 3 * 16 KB = 48 KB each, 96 KB total.
  __shared__ __align__(16) signed char ldsA[3][BM * KB];
  __shared__ __align__(16) signed char ldsB[3][BN * KB];
  const int t = threadIdx.x;
  const int lane = t & 63;
  const int wave = t >> 6;
  const int wm = wave >> 1;  // 0..3 (M quarter, 64 rows)
  const int wn = wave & 1;   // 0..1 (N half, 128 cols)

  // XCD-chunked swizzle: 512 blocks, 64/XCD -> per-XCD A slice 4 MB (one L2).
  const int nbn = N / BN;  // 4
  const int bid = blockIdx.x;
  const int tile = (bid & 7) * cpx + (bid >> 3);
  const int bm = tile / nbn, bn = tile % nbn;

  // K-blocked layout: operand tile kt is CONTIGUOUS 16 KB at
  // q + kt*R*64 + tilerow0*64.
  const size_t kbA = (size_t)M * KB;
  const size_t kbB = (size_t)N * KB;
  const signed char* Abase = Aq + (size_t)bm * BM * KB;
  const signed char* Bbase = Bq + (size_t)bn * BN * KB;

  // Staging: 16 KB tile = 2 stmts x (512 thr x 16 B). LDS dest linear at
  // stmt*8192 + t*16; source pre-swizzled: chunk field (bits 4-5 of t*16)
  // XORed with (row>>1)&3 = (t>>3)&3.
  const int ssoff = (t * 16) ^ (((t >> 3) & 3) << 4);
  const int sdst = t * 16;

  // Fragment reads (swizzled): row r, k-chunk fq -> r*64 + ((fq^((r>>1)&3))<<4);
  // (r>>1)&3 == (fr>>1)&3 for all our row forms (wm*64/wn*128/m*16 ≡ 0 mod 8).
  const int fr = lane & 15, fq = lane >> 4;
  const int xr = (fr >> 1) & 3;
  int aoff[4], boff[8];
#pragma unroll
  for (int m = 0; m < 4; ++m)
    aoff[m] = (wm * 64 + m * 16 + fr) * KB + ((fq ^ xr) << 4);
#pragma unroll
  for (int n = 0; n < 8; ++n)
    boff[n] = (wn * 128 + n * 16 + fr) * KB + ((fq ^ xr) << 4);

  i32x4 acc[4][8];
#pragma unroll
  for (int m = 0; m < 4; ++m)
#pragma unroll
    for (int n = 0; n < 8; ++n) acc[m][n] = (i32x4){0, 0, 0, 0};

#define STAGE_A(bf, kt)                                                    \
  do {                                                                    \
    const signed char* ga = Abase + (size_t)(kt) * kbA;                   \
    gload_lds16(ga + ssoff, &ldsA[bf][sdst]);                             \
    gload_lds16(ga + 8192 + ssoff, &ldsA[bf][8192 + sdst]);               \
  } while (0)
#define STAGE_B(bf, kt)                                                    \
  do {                                                                    \
    const signed char* gb = Bbase + (size_t)(kt) * kbB;                   \
    gload_lds16(gb + ssoff, &ldsB[bf][sdst]);                             \
    gload_lds16(gb + 8192 + ssoff, &ldsB[bf][8192 + sdst]);               \
  } while (0)

  const int NT = K / KB;  // 16
  // Prologue: stage tiles 0,1; wait tile 0 (tile 1's 4 stay in flight).
  STAGE_A(0, 0);
  STAGE_B(0, 0);
  STAGE_A(1, 1);
  STAGE_B(1, 1);
  asm volatile("s_waitcnt vmcnt(4)" ::: "memory");
  __builtin_amdgcn_s_barrier();

  int cb = 0;  // buffer holding tile kt
  for (int kt = 0; kt < NT; ++kt) {
    const signed char* lA = ldsA[cb];
    const signed char* lB = ldsB[cb];
    int sb = cb + 2;
    if (sb >= 3) sb -= 3;
    const bool p2 = (kt + 2 < NT), p1 = (kt + 1 < NT);

    i32x4 a[4], b0, b1;
    // ---- phase 0: a[0..3] + b0,b1 reads; stage next-next A; 8 MFMA ----
#pragma unroll
    for (int m = 0; m < 4; ++m)
      a[m] = *reinterpret_cast<const i32x4*>(lA + aoff[m]);
    b0 = *reinterpret_cast<const i32x4*>(lB + boff[0]);
    b1 = *reinterpret_cast<const i32x4*>(lB + boff[1]);
    if (p2) STAGE_A(sb, kt + 2);
    __builtin_amdgcn_s_barrier();
    __builtin_amdgcn_s_setprio(1);
#pragma unroll
    for (int m = 0; m < 4; ++m) {
      acc[m][0] = __builtin_amdgcn_mfma_i32_16x16x64_i8(a[m], b0, acc[m][0], 0, 0, 0);
      acc[m][1] = __builtin_amdgcn_mfma_i32_16x16x64_i8(a[m], b1, acc[m][1], 0, 0, 0);
    }
    __builtin_amdgcn_s_setprio(0);
    __builtin_amdgcn_s_barrier();

    // ---- phase 1: b2,b3; stage next-next B; 8 MFMA ----
    b0 = *reinterpret_cast<const i32x4*>(lB + boff[2]);
    b1 = *reinterpret_cast<const i32x4*>(lB + boff[3]);
    if (p2) STAGE_B(sb, kt + 2);
    __builtin_amdgcn_s_barrier();
    __builtin_amdgcn_s_setprio(1);
#pragma unroll
    for (int m = 0; m < 4; ++m) {
      acc[m][2] = __builtin_amdgcn_mfma_i32_16x16x64_i8(a[m], b0, acc[m][2], 0, 0, 0);
      acc[m][3] = __builtin_amdgcn_mfma_i32_16x16x64_i8(a[m], b1, acc[m][3], 0, 0, 0);
    }
    __builtin_amdgcn_s_setprio(0);
    __builtin_amdgcn_s_barrier();

    // ---- phase 2: b4,b5; 8 MFMA ----
    b0 = *reinterpret_cast<const i32x4*>(lB + boff[4]);
    b1 = *reinterpret_cast<const i32x4*>(lB + boff[5]);
    __builtin_amdgcn_s_barrier();
    __builtin_amdgcn_s_setprio(1);
#pragma unroll
    for (int m = 0; m < 4; ++m) {
      acc[m][4] = __builtin_amdgcn_mfma_i32_16x16x64_i8(a[m], b0, acc[m][4], 0, 0, 0);
      acc[m][5] = __builtin_amdgcn_mfma_i32_16x16x64_i8(a[m], b1, acc[m][5], 0, 0, 0);
    }
    __builtin_amdgcn_s_setprio(0);
    __builtin_amdgcn_s_barrier();

    // ---- phase 3: b6,b7; 8 MFMA; counted vmcnt at iter end ----
    b0 = *reinterpret_cast<const i32x4*>(lB + boff[6]);
    b1 = *reinterpret_cast<const i32x4*>(lB + boff[7]);
    __builtin_amdgcn_s_barrier();
    __builtin_amdgcn_s_setprio(1);
#pragma unroll
    for (int m = 0; m < 4; ++m) {
      acc[m][6] = __builtin_amdgcn_mfma_i32_16x16x64_i8(a[m], b0, acc[m][6], 0, 0, 0);
      acc[m][7] = __builtin_amdgcn_mfma_i32_16x16x64_i8(a[m], b1, acc[m][7], 0, 0, 0);
    }
    __builtin_amdgcn_s_setprio(0);
    // kt+1's 4 stmts (issued LAST iter = full-iter cover) retired; kt+2's 4
    // stay in flight ACROSS the barrier. Tail: drain to 0.
    if (p1) {
      if (p2)
        asm volatile("s_waitcnt vmcnt(4)" ::: "memory");
      else
        asm volatile("s_waitcnt vmcnt(0)" ::: "memory");
    }
    __builtin_amdgcn_s_barrier();
    cb = (cb + 1 == 3) ? 0 : cb + 1;
  }
#undef STAGE_A
#undef STAGE_B

  // Epilogue: C/D layout col = lane&15, row = (lane>>4)*4 + reg.
  // Per (m,r) the 8 n-stores write 512 B contiguous per row (full L2 lines).
  const int row0 = bm * BM + wm * 64;
  const int col0 = bn * BN + wn * 128;
  const float C = 1.0f / 16129.0f;
  float wmx[8], bs[8];
#pragma unroll
  for (int n = 0; n < 8; ++n) {
    int col = col0 + n * 16 + fr;
    wmx[n] = Bmax[col];
    bs[n] = bias[col];
  }
#pragma unroll
  for (int m = 0; m < 4; ++m) {
#pragma unroll
    for (int r = 0; r < 4; ++r) {
      int row = row0 + m * 16 + fq * 4 + r;
      float xm = Amax[row];
      float* orow = out + (size_t)row * N;
#pragma unroll
      for (int n = 0; n < 8; ++n) {
        float v = (float)acc[m][n][r] * C;
        float h = __half2float(__float2half_rn(v));  // fp16 rounding step
        orow[col0 + n * 16 + fr] = h * (xm * wmx[n]) + bs[n];
      }
    }
  }
}

extern "C" void kernel_launch(void* const* d_in, const int* in_sizes, int n_in,
                              void* d_out, int out_size, void* d_ws, size_t ws_size,
                              hipStream_t stream) {
  const float* x = (const float*)d_in[0];     // [B,S,K] fp32
  const float* w = (const float*)d_in[1];     // [N,K] fp32
  const float* bias = (const float*)d_in[2];  // [N] fp32
  float* out = (float*)d_out;                 // [B,S,N] fp32

  const int N = in_sizes[2];
  const int K = in_sizes[1] / N;   // 1024
  const int M = in_sizes[0] / K;   // 32768

  // workspace layout: x_q | w_q | x_max | w_max  (~34.7 MB total)
  signed char* xq = (signed char*)d_ws;
  signed char* wq = xq + (size_t)M * K;
  float* xmax = (float*)(wq + (size_t)N * K);
  float* wmax = xmax + M;

  quant_rows_kernel<<<M, 256, 0, stream>>>(x, xq, xmax, K, M);
  quant_rows_kernel<<<N, 256, 0, stream>>>(w, wq, wmax, K, N);

  const int nwg = (M / BM) * (N / BN);  // 512, divisible by 8
  const int cpx = nwg / 8;
  w8x8_gemm_kernel<<<nwg, 512, 0, stream>>>(xq, wq, xmax, wmax, bias, out,
                                            M, N, K, cpx);
}

// Round 10
// 89.130 us; speedup vs baseline: 1.1082x; 1.1082x over previous
//
#include <hip/hip_runtime.h>
#include <hip/hip_fp16.h>

// W8X8Linear: per-row int8 quant (x and w), int8 GEMM via MFMA, dequant+bias.
// M=B*S=32768, N=1024, K=1024 (derived from in_sizes at launch).
//
// Exact-replication notes:
//  - jnp.round == round-half-even == rintf (v_rndne_f32)
//  - scale 127.0f/max (fp32 div) then fp32 mul, like the reference
//  - int32 accumulation == reference's fp32 einsum (|acc| < 2^24, exact)
//  - dequant: * (1/16129), fp16 RN cast, fp32 * (xmax*wmax) + bias
//
// R1: dbuf+XCD swizzle: 92us GEMM. R2/R7/R8: three schedule-structure
//     variants (counted vmcnt, 4-phase 256^2): ALL NULL. R3: no-LDS reg
//     GEMM: 158us. R4: coarse 256^2: 117us. R5: min-waves clamp with
//     128-reg acc -> spill -> 360us. R6: K-BLOCKED quant layout
//     (contiguous staging): 95us total (~65us GEMM) — the one real win.
// R9: DIAGNOSIS: every structure = serial sum of pipes because occupancy
//     is 2 waves/SIMD: reported VGPR 104 EXCLUDES 64 acc AGPRs; unified
//     gfx950 file -> ~168 regs -> 2 waves/SIMD. No TLP -> nothing overlaps.
//     FIX: thin to <=128 total (BK=64, 4+4 frag offsets, acc 64, a/b 32)
//     + __launch_bounds__(256,4) -> 4 waves/SIMD, 4 blocks/CU co-resident.
//     (Differs from R5: live set actually fits; R5's acc alone was 128.)

typedef int i32x4 __attribute__((ext_vector_type(4)));

#define BM 128
#define BN 128
#define KB 64  // K-bytes per tile = quant layout block size

// -------- quantize: one block per row; OUTPUT IS K-BLOCKED q[kb][row][64] ---
__global__ __launch_bounds__(256) void quant_rows_kernel(
    const float* __restrict__ in, signed char* __restrict__ q,
    float* __restrict__ rowmax, int K, int R) {
  const int row = blockIdx.x;
  const int t = threadIdx.x;
  const size_t base = (size_t)row * K;
  float4 v = reinterpret_cast<const float4*>(in + base)[t];
  float a = fmaxf(fmaxf(fabsf(v.x), fabsf(v.y)), fmaxf(fabsf(v.z), fabsf(v.w)));
#pragma unroll
  for (int off = 32; off > 0; off >>= 1) a = fmaxf(a, __shfl_xor(a, off, 64));
  __shared__ float smax[4];
  if ((t & 63) == 0) smax[t >> 6] = a;
  __syncthreads();
  float m = fmaxf(fmaxf(smax[0], smax[1]), fmaxf(smax[2], smax[3]));
  float s = 127.0f / m;  // fp32 divide, same as reference
  char4 qq;
  qq.x = (signed char)(int)rintf(v.x * s);
  qq.y = (signed char)(int)rintf(v.y * s);
  qq.z = (signed char)(int)rintf(v.z * s);
  qq.w = (signed char)(int)rintf(v.w * s);
  // elems k = 4t..4t+3 -> kb = t>>4, within-block byte (t&15)*4
  const int kb = t >> 4;
  signed char* dst = q + (size_t)kb * R * KB + (size_t)row * KB + (t & 15) * 4;
  *reinterpret_cast<char4*>(dst) = qq;
  if (t == 0) rowmax[row] = m;
}

// ---------------- int8 GEMM, 128x128 tile, 4 waves (2x2), BK=64 -------------
__device__ __forceinline__ void gload_lds16(const void* g, void* l) {
  __builtin_amdgcn_global_load_lds(
      (const __attribute__((address_space(1))) unsigned char*)g,
      (__attribute__((address_space(3))) unsigned char*)l, 16, 0, 0);
}

__global__ __launch_bounds__(256, 4) void w8x8_gemm_kernel(
    const signed char* __restrict__ Aq, const signed char* __restrict__ Bq,
    const float* __restrict__ Amax, const float* __restrict__ Bmax,
    const float* __restrict__ bias, float* __restrict__ out,
    int M, int N, int K, int cpx) {
  // 2 buffers x (A 8 KB + B 8 KB) = 32 KB -> 4 blocks/CU (VGPR-bound).
  __shared__ __align__(16) signed char ldsA[2][BM * KB];
  __shared__ __align__(16) signed char ldsB[2][BN * KB];
  const int t = threadIdx.x;
  const int lane = t & 63;
  const int wave = t >> 6;
  const int wrow = wave >> 1, wcol = wave & 1;

  // XCD-chunked swizzle: contiguous bm-run per XCD (A slice 4 MB = one L2).
  const int nbn = N / BN;
  const int bid = blockIdx.x;
  const int tile = (bid & 7) * cpx + (bid >> 3);
  const int bm = tile / nbn, bn = tile % nbn;

  // K-blocked layout: operand tile kt is CONTIGUOUS 8 KB at
  // q + kt*R*64 + tilerow0*64.
  const size_t kbA = (size_t)M * KB;
  const size_t kbB = (size_t)N * KB;
  const signed char* Abase = Aq + (size_t)bm * BM * KB;
  const signed char* Bbase = Bq + (size_t)bn * BN * KB;

  // Staging: 8 KB/operand = 512 16B-chunks = 2 stmts x 256 thr. LDS dest
  // linear (chunk c -> byte c*16). Source pre-swizzled: physical chunk p of
  // row r holds logical chunk p ^ ((r>>1)&3). Chunk t: r=t>>2; chunk t+256:
  // r+64 -> same (r>>1)&3. One offset serves both stmts (+4096).
  const int rS = t >> 2;
  const int gs0 = (rS << 6) | ((((t & 3) ^ ((rS >> 1) & 3))) << 4);
  const int dst0 = t * 16;

  // Fragment reads (swizzled): frag row ra, k-chunk fq -> physical chunk
  // fq ^ ((ra>>1)&3); (ra>>1)&3 == (fr>>1)&3 (row bases are multiples of 16).
  // Bank pattern: 2-way within 16-lane groups, uniform across wave = free.
  const int fr = lane & 15, fq = lane >> 4;
  const int pcs = (fq ^ ((fr >> 1) & 3)) << 4;
  int aoff[4], boff[4];
#pragma unroll
  for (int m = 0; m < 4; ++m) {
    aoff[m] = (wrow * 64 + m * 16 + fr) * KB + pcs;
    boff[m] = (wcol * 64 + m * 16 + fr) * KB + pcs;
  }

  i32x4 acc[4][4];
#pragma unroll
  for (int m = 0; m < 4; ++m)
#pragma unroll
    for (int n = 0; n < 4; ++n) acc[m][n] = (i32x4){0, 0, 0, 0};

#define STAGE(bf, kt)                                                  \
  do {                                                                 \
    const signed char* ga = Abase + (size_t)(kt) * kbA + gs0;          \
    const signed char* gb = Bbase + (size_t)(kt) * kbB + gs0;          \
    gload_lds16(ga, &ldsA[bf][dst0]);                                  \
    gload_lds16(ga + 4096, &ldsA[bf][dst0 + 4096]);                    \
    gload_lds16(gb, &ldsB[bf][dst0]);                                  \
    gload_lds16(gb + 4096, &ldsB[bf][dst0 + 4096]);                    \
  } while (0)

  const int NT = K / KB;  // 16
  STAGE(0, 0);

  for (int kt = 0; kt < NT; ++kt) {
    const bool pf = (kt + 1 < NT);
    if (pf) STAGE((kt + 1) & 1, kt + 1);
    // Tile kt's 4 loads (issued LAST iter = full-iter cover) retired;
    // kt+1's 4 stay in flight across the barrier.
    if (pf)
      asm volatile("s_waitcnt vmcnt(4)" ::: "memory");
    else
      asm volatile("s_waitcnt vmcnt(0)" ::: "memory");
    __builtin_amdgcn_s_barrier();

    const signed char* lA = ldsA[kt & 1];
    const signed char* lB = ldsB[kt & 1];
    i32x4 a[4], b[4];
#pragma unroll
    for (int m = 0; m < 4; ++m) {
      a[m] = *reinterpret_cast<const i32x4*>(lA + aoff[m]);
      b[m] = *reinterpret_cast<const i32x4*>(lB + boff[m]);
    }
    __builtin_amdgcn_s_setprio(1);
#pragma unroll
    for (int m = 0; m < 4; ++m)
#pragma unroll
      for (int n = 0; n < 4; ++n)
        acc[m][n] = __builtin_amdgcn_mfma_i32_16x16x64_i8(a[m], b[n],
                                                          acc[m][n], 0, 0, 0);
    __builtin_amdgcn_s_setprio(0);

    // Protect buf (kt+1)&1 from next iteration's stage.
    if (pf) __builtin_amdgcn_s_barrier();
  }
#undef STAGE

  // Epilogue: C/D layout col = lane&15, row = (lane>>4)*4 + reg.
  const int row0 = bm * BM + wrow * 64;
  const int col0 = bn * BN + wcol * 64;
  const float C = 1.0f / 16129.0f;
  float wmx[4], bs[4];
#pragma unroll
  for (int n = 0; n < 4; ++n) {
    int col = col0 + n * 16 + fr;
    wmx[n] = Bmax[col];
    bs[n] = bias[col];
  }
#pragma unroll
  for (int m = 0; m < 4; ++m) {
#pragma unroll
    for (int r = 0; r < 4; ++r) {
      int row = row0 + m * 16 + fq * 4 + r;
      float xm = Amax[row];
      float* orow = out + (size_t)row * N;
#pragma unroll
      for (int n = 0; n < 4; ++n) {
        float v = (float)acc[m][n][r] * C;
        float h = __half2float(__float2half_rn(v));  // fp16 rounding step
        orow[col0 + n * 16 + fr] = h * (xm * wmx[n]) + bs[n];
      }
    }
  }
}

extern "C" void kernel_launch(void* const* d_in, const int* in_sizes, int n_in,
                              void* d_out, int out_size, void* d_ws, size_t ws_size,
                              hipStream_t stream) {
  const float* x = (const float*)d_in[0];     // [B,S,K] fp32
  const float* w = (const float*)d_in[1];     // [N,K] fp32
  const float* bias = (const float*)d_in[2];  // [N] fp32
  float* out = (float*)d_out;                 // [B,S,N] fp32

  const int N = in_sizes[2];
  const int K = in_sizes[1] / N;   // 1024
  const int M = in_sizes[0] / K;   // 32768

  // workspace layout: x_q | w_q | x_max | w_max  (~34.7 MB total)
  signed char* xq = (signed char*)d_ws;
  signed char* wq = xq + (size_t)M * K;
  float* xmax = (float*)(wq + (size_t)N * K);
  float* wmax = xmax + M;

  quant_rows_kernel<<<M, 256, 0, stream>>>(x, xq, xmax, K, M);
  quant_rows_kernel<<<N, 256, 0, stream>>>(w, wq, wmax, K, N);

  const int nwg = (M / BM) * (N / BN);  // 2048, divisible by 8
  const int cpx = nwg / 8;
  w8x8_gemm_kernel<<<nwg, 256, 0, stream>>>(xq, wq, xmax, wmax, bias, out,
                                            M, N, K, cpx);
}